// Round 3
// baseline (2311.994 us; speedup 1.0000x reference)
//
#include <hip/hip_runtime.h>

#define H 192
#define W 192
#define HW (H*W)
#define G 32          // feature/ctx channels
#define C 64          // x channels
#define C2 128        // mean+var channels
#define C1 68         // conv1 out channels
#define B 6           // output batches
#define NB 2          // distinct ctx batches
#define OUTC 260      // 68 + 3*64
#define RROWS 16
#define NSTRIP (H / RROWS)   // 12

// K1: img_ctx[b][o][p] = b_ctx[o] + sum_k w_ctx[o][k] * feature[b][k][p], b in 0..1
__global__ __launch_bounds__(256) void ctx_kernel(
    const float* __restrict__ feature, const float* __restrict__ w_ctx,
    const float* __restrict__ b_ctx, float* __restrict__ ctx)
{
    int p = blockIdx.x * 256 + threadIdx.x;
    int b = blockIdx.y;
    float f[G];
    const float* fp = feature + (size_t)b * G * HW + p;
#pragma unroll
    for (int k = 0; k < G; k++) f[k] = fp[k * HW];
    float* op = ctx + (size_t)b * G * HW + p;
    for (int o = 0; o < G; o++) {
        float acc = b_ctx[o];
#pragma unroll
        for (int k = 0; k < G; k++) acc += w_ctx[o * G + k] * f[k];
        op[o * HW] = acc;
    }
}

// K2: out[b][o][p] = b1[o] + sum_c w1[o][c] * x[b][c][p], o in 0..67
__global__ __launch_bounds__(256) void conv1_kernel(
    const float* __restrict__ ctx, const float* __restrict__ extra,
    const float* __restrict__ w1, const float* __restrict__ b1,
    float* __restrict__ out)
{
    int p = blockIdx.x * 256 + threadIdx.x;
    int b = blockIdx.y;
    float xv[C];
    const float* cp = ctx + (size_t)(b / 3) * G * HW + p;
#pragma unroll
    for (int k = 0; k < G; k++) xv[k] = cp[k * HW];
    const float* ep = extra + (size_t)b * G * HW + p;
#pragma unroll
    for (int k = 0; k < G; k++) xv[G + k] = ep[k * HW];
    float* op = out + (size_t)b * OUTC * HW + p;
    for (int o = 0; o < C1; o++) {
        float acc = b1[o];
#pragma unroll
        for (int k = 0; k < C; k++) acc += w1[o * C + k] * xv[k];
        op[o * HW] = acc;
    }
}

// Pack transposed weights + biases for the 3 scales:
// wTb[si][c][0..63] = w_s[si][o][c]      (mean part, o index fastest)
// wTb[si][c][64..127] = w_s[si][o][64+c] (var part)
// then 3*64 biases at the end.
__global__ __launch_bounds__(256) void prep_w_kernel(
    const float* __restrict__ w0, const float* __restrict__ b0,
    const float* __restrict__ w1, const float* __restrict__ b1,
    const float* __restrict__ w2, const float* __restrict__ b2,
    float* __restrict__ wTb)
{
    int i = blockIdx.x * 256 + threadIdx.x;
    int total = 3 * C * C2;
    if (i < total) {
        int si = i / (C * C2);
        int r = i % (C * C2);
        int o = r / C2, cc = r % C2;
        const float* w = (si == 0) ? w0 : (si == 1) ? w1 : w2;
        int c = cc & 63, mv = cc >> 6;
        wTb[si * C * C2 + c * C2 + mv * C + o] = w[o * C2 + cc];
    } else if (i < total + 3 * C) {
        int j = i - total;
        int si = j / C, o = j % C;
        const float* bb = (si == 0) ? b0 : (si == 1) ? b1 : b2;
        wTb[total + si * C + o] = bb[o];
    }
}

// K3: fully fused box mean/var + 1x1 conv(128->64), all scales/batches in one grid.
// grid: (NSTRIP, B, 3si); block: 192 threads = one per column.
// Vertical box sums held as running state in LDS; horizontal clamped window
// read from LDS; conv accumulated per-pixel in registers; writes out directly.
__global__ __launch_bounds__(192) void fused_kernel(
    const float* __restrict__ ctx, const float* __restrict__ extra,
    const float* __restrict__ wTb, float* __restrict__ out)
{
    __shared__ float vs1[C][W];
    __shared__ float vs2[C][W];
    int w = threadIdx.x;
    int h0 = blockIdx.x * RROWS;
    int b = blockIdx.y;
    int si = blockIdx.z;
    int half = 2 << si;   // 2,4,8
    const float* src0 = ctx + (size_t)(b / 3) * G * HW;
    const float* src1 = extra + (size_t)b * G * HW;
    const float* wsi = wTb + si * C * C2;
    const float* bsi = wTb + 3 * C * C2 + si * C;

    // init vertical window state at row h0
    int ya = max(h0 - half, 0);
    int yb = min(h0 + half, H - 1);
#pragma unroll 1
    for (int c = 0; c < C; c++) {
        const float* src = (c < G) ? (src0 + c * HW) : (src1 + (c - G) * HW);
        float t1 = 0.f, t2 = 0.f;
        for (int y = ya; y <= yb; y++) { float v = src[y * W + w]; t1 += v; t2 += v * v; }
        vs1[c][w] = t1; vs2[c][w] = t2;
    }
    __syncthreads();

    int x0 = max(w - half, 0);
    int x1 = min(w + half, W - 1);
    float ncols = (float)(x1 - x0 + 1);
    float* outp = out + ((size_t)b * OUTC + C1 + si * C) * HW;

    for (int h = h0; h < h0 + RROWS; h++) {
        if (h > h0) {
            int yadd = h + half;
            int ysub = h - half - 1;
            bool da = (yadd <= H - 1), dsb = (ysub >= 0);
#pragma unroll 1
            for (int c = 0; c < C; c++) {
                const float* src = (c < G) ? (src0 + c * HW) : (src1 + (c - G) * HW);
                float va = da ? src[yadd * W + w] : 0.f;
                float vb = dsb ? src[ysub * W + w] : 0.f;
                vs1[c][w] += va - vb;
                vs2[c][w] += va * va - vb * vb;
            }
            __syncthreads();
        }
        int nrows = min(h + half, H - 1) - max(h - half, 0) + 1;
        float inv_area = 1.f / ((float)nrows * ncols);

        float acc[C];
#pragma unroll
        for (int o = 0; o < C; o++) acc[o] = 0.f;

#pragma unroll 1
        for (int c = 0; c < C; c++) {
            float t1 = 0.f, t2 = 0.f;
            for (int x = x0; x <= x1; x++) { t1 += vs1[c][x]; t2 += vs2[c][x]; }
            float mean = t1 * inv_area;
            float var  = t2 * inv_area - mean * mean;
            const float* wrow = wsi + c * C2;
#pragma unroll
            for (int o = 0; o < C; o++)
                acc[o] += wrow[o] * mean + wrow[C + o] * var;
        }
        __syncthreads();   // WAR guard before next row's LDS update
#pragma unroll
        for (int o = 0; o < C; o++)
            outp[(size_t)o * HW + h * W + w] = acc[o] + bsi[o];
    }
}

extern "C" void kernel_launch(void* const* d_in, const int* in_sizes, int n_in,
                              void* d_out, int out_size, void* d_ws, size_t ws_size,
                              hipStream_t stream) {
    const float* feature = (const float*)d_in[0];
    const float* extra   = (const float*)d_in[1];
    const float* w_ctx   = (const float*)d_in[2];
    const float* b_ctx   = (const float*)d_in[3];
    const float* w1      = (const float*)d_in[4];
    const float* b1      = (const float*)d_in[5];
    float* out = (float*)d_out;

    float* ctx = (float*)d_ws;                       // NB*G*HW floats
    float* wTb = ctx + (size_t)NB * G * HW;          // 3*C*C2 + 3*C floats

    prep_w_kernel<<<dim3((3 * C * C2 + 3 * C + 255) / 256), 256, 0, stream>>>(
        (const float*)d_in[6], (const float*)d_in[7],
        (const float*)d_in[8], (const float*)d_in[9],
        (const float*)d_in[10], (const float*)d_in[11], wTb);
    ctx_kernel<<<dim3(HW / 256, NB), 256, 0, stream>>>(feature, w_ctx, b_ctx, ctx);
    conv1_kernel<<<dim3(HW / 256, B), 256, 0, stream>>>(ctx, extra, w1, b1, out);
    fused_kernel<<<dim3(NSTRIP, B, 3), 192, 0, stream>>>(ctx, extra, wTb, out);
}